// Round 7
// baseline (774.328 us; speedup 1.0000x reference)
//
#include <hip/hip_runtime.h>
#include <hip/hip_bf16.h>

#define B_ 8
#define S_ 2048
#define H_ 256
#define Z_ 64
#define CHK 32            // k-chunk staged per iteration
#define NCHK (S_/CHK)     // 64
#define KLD 264           // K LDS row stride (shorts): 528 B; 16B-unit stride 33 -> 2-way (free) b128 phases
#define PSLD 40           // Ps row stride (shorts): 80 B; unit stride 5 -> conflict-free b128

typedef short bf16x8 __attribute__((ext_vector_type(8)));
typedef float f32x4 __attribute__((ext_vector_type(4)));

__device__ __forceinline__ unsigned short f2bf(float f) {
  __hip_bfloat16 h = __float2bfloat16(f);
  return *reinterpret_cast<unsigned short*>(&h);
}
__device__ __forceinline__ float bf2f(unsigned short u) {
  __hip_bfloat16 h;
  *reinterpret_cast<unsigned short*>(&h) = u;
  return __bfloat162float(h);
}

// ---------------------------------------------------------------------------
// k0: per-batch encoder-part projections: q0/k0/v0[b][h] = sum_d enc[b][d]*W[d][h]
__global__ __launch_bounds__(256) void k0_base(
    const float* __restrict__ enc, const float* __restrict__ Wq,
    const float* __restrict__ Wk, const float* __restrict__ Wv,
    float* __restrict__ q0, float* __restrict__ k0, float* __restrict__ v0) {
  int b = blockIdx.x;
  int h = threadIdx.x;
  __shared__ float encs[H_];
  encs[h] = enc[b*H_ + h] + enc[B_*H_ + b*H_ + h];  // sum over 2 dirs
  __syncthreads();
  float aq = 0.f, ak = 0.f, av = 0.f;
  #pragma unroll 4
  for (int d = 0; d < H_; d++) {
    float e = encs[d];
    aq = fmaf(e, Wq[d*H_ + h], aq);
    ak = fmaf(e, Wk[d*H_ + h], ak);
    av = fmaf(e, Wv[d*H_ + h], av);
  }
  q0[b*H_ + h] = aq;
  k0[b*H_ + h] = ak;
  v0[b*H_ + h] = av;
}

// ---------------------------------------------------------------------------
// k1: z-part projection (fp32) + hi/lo bf16 split for Q,K; V -> bf16 transposed Vt[b][h][k]
__global__ __launch_bounds__(256) void k1_prep(
    const float* __restrict__ z, const float* __restrict__ Wq,
    const float* __restrict__ Wk, const float* __restrict__ Wv,
    const float* __restrict__ q0, const float* __restrict__ k0b, const float* __restrict__ v0,
    unsigned short* __restrict__ Qhi, unsigned short* __restrict__ Qlo,
    unsigned short* __restrict__ Khi, unsigned short* __restrict__ Klo,
    unsigned short* __restrict__ Vt) {
  int b  = blockIdx.x >> 7;   // 128 tiles of 16 s each
  int st = blockIdx.x & 127;
  int tid = threadIdx.x;      // tid = h
  __shared__ float zs[16*Z_];
  __shared__ float vbuf[16][H_];
  {
    const float4* zp = reinterpret_cast<const float4*>(z + ((size_t)b*S_ + st*16)*Z_);
    reinterpret_cast<float4*>(zs)[tid] = zp[tid];
  }
  __syncthreads();
  float bq = q0[b*H_ + tid], bk = k0b[b*H_ + tid], bv = v0[b*H_ + tid];
  float accq[16], acck[16], accv[16];
  #pragma unroll
  for (int s = 0; s < 16; s++) { accq[s] = bq; acck[s] = bk; accv[s] = bv; }
  #pragma unroll 2
  for (int z0 = 0; z0 < Z_; z0 += 8) {
    float wq[8], wk[8], wv[8];
    #pragma unroll
    for (int j = 0; j < 8; j++) {
      wq[j] = Wq[(H_+z0+j)*H_ + tid];
      wk[j] = Wk[(H_+z0+j)*H_ + tid];
      wv[j] = Wv[(H_+z0+j)*H_ + tid];
    }
    #pragma unroll
    for (int j = 0; j < 8; j++) {
      #pragma unroll
      for (int s = 0; s < 16; s++) {
        float zz = zs[s*Z_ + z0 + j];
        accq[s] = fmaf(zz, wq[j], accq[s]);
        acck[s] = fmaf(zz, wk[j], acck[s]);
        accv[s] = fmaf(zz, wv[j], accv[s]);
      }
    }
  }
  #pragma unroll
  for (int s = 0; s < 16; s++) {
    size_t row = ((size_t)b*S_ + st*16 + s)*H_ + tid;
    unsigned short qh = f2bf(accq[s]);
    Qhi[row] = qh;
    Qlo[row] = f2bf(accq[s] - bf2f(qh));
    unsigned short kh = f2bf(acck[s]);
    Khi[row] = kh;
    Klo[row] = f2bf(acck[s] - bf2f(kh));
    vbuf[s][tid] = accv[s];
  }
  __syncthreads();
  // transpose V: thread h writes 16 consecutive k as bf16 (32B contiguous)
  unsigned int pk[8];
  #pragma unroll
  for (int j = 0; j < 8; j++) {
    pk[j] = (unsigned int)f2bf(vbuf[2*j][tid]) |
            ((unsigned int)f2bf(vbuf[2*j+1][tid]) << 16);
  }
  uint4* vt4 = reinterpret_cast<uint4*>(Vt + ((size_t)b*H_ + tid)*S_ + st*16);
  vt4[0] = make_uint4(pk[0], pk[1], pk[2], pk[3]);
  vt4[1] = make_uint4(pk[4], pk[5], pk[6], pk[7]);
}

// ---------------------------------------------------------------------------
// k2: flash attention. Block = 64 q rows (wave w owns rows w*16..w*16+15),
// K staged in double-buffered LDS (shared by all waves); V fragments straight
// from global (L2-hot). attn gets RAW fp32 scores during the sweep; the tail
// applies exp(se - m_fin)*il elementwise (no m-history needed).
__global__ __launch_bounds__(256, 2) void k2_flash(
    const unsigned short* __restrict__ Qhi, const unsigned short* __restrict__ Qlo,
    const unsigned short* __restrict__ Khi, const unsigned short* __restrict__ Klo,
    const unsigned short* __restrict__ Vt, const int* __restrict__ mask,
    float* __restrict__ attn, float* __restrict__ outp) {
  int b    = blockIdx.x >> 5;   // 32 blocks of 64 q per batch
  int qt   = blockIdx.x & 31;
  int qb   = qt*64;
  int tid  = threadIdx.x;
  int wave = tid >> 6;
  int lane = tid & 63;
  int l15  = lane & 15;
  int quad = lane >> 4;
  int qw   = qb + wave*16;      // this wave's q base (within batch)

  __shared__ __align__(16) unsigned short KhiL[2][32*KLD];   // 33.0 KB
  __shared__ __align__(16) unsigned short KloL[2][32*KLD];   // 33.0 KB
  __shared__ __align__(16) unsigned short Ps[4][16*PSLD];    //  5.0 KB
  __shared__ float Mfin[4][16], Ilin[4][16];                 //  0.5 KB
  // total ~71.5 KB -> 2 blocks/CU

  const unsigned short* KhiB = Khi + (size_t)b*S_*H_;
  const unsigned short* KloB = Klo + (size_t)b*S_*H_;
  const unsigned short* VtB  = Vt  + (size_t)b*H_*S_;

  uint4 rkh[4], rkl[4];   // staging relay registers

  auto stage_issue = [&](int c) {
    int kc = c*CHK;
    const uint4* ph = reinterpret_cast<const uint4*>(KhiB + (size_t)kc*H_);
    const uint4* pl = reinterpret_cast<const uint4*>(KloB + (size_t)kc*H_);
    #pragma unroll
    for (int i = 0; i < 4; i++) {
      rkh[i] = ph[i*256 + tid];    // chunk is 16 KB contiguous
      rkl[i] = pl[i*256 + tid];
    }
  };
  auto stage_write = [&](int buf) {
    #pragma unroll
    for (int i = 0; i < 4; i++) {
      int idx = i*256 + tid;
      int row = idx >> 5, col = idx & 31;   // 32 x 16B per K row
      *reinterpret_cast<uint4*>(&KhiL[buf][row*KLD + col*8]) = rkh[i];
      *reinterpret_cast<uint4*>(&KloL[buf][row*KLD + col*8]) = rkl[i];
    }
  };

  // Q fragments: A[m=l15][k=quad*8+j], 8 d-chunks, hi+lo
  bf16x8 qh[8], ql[8];
  {
    const unsigned short* qhp = Qhi + ((size_t)b*S_ + qw + l15)*H_ + quad*8;
    const unsigned short* qlp = Qlo + ((size_t)b*S_ + qw + l15)*H_ + quad*8;
    #pragma unroll
    for (int dc = 0; dc < 8; dc++) {
      qh[dc] = *reinterpret_cast<const bf16x8*>(qhp + dc*32);
      ql[dc] = *reinterpret_cast<const bf16x8*>(qlp + dc*32);
    }
  }
  int mrow[4];
  #pragma unroll
  for (int r = 0; r < 4; r++) mrow[r] = mask[b*S_ + qw + quad*4 + r];

  f32x4 acc_o[16];
  #pragma unroll
  for (int ht = 0; ht < 16; ht++) acc_o[ht] = (f32x4){0.f, 0.f, 0.f, 0.f};
  float m_run[4] = {-1e30f, -1e30f, -1e30f, -1e30f};
  float l_run[4] = {0.f, 0.f, 0.f, 0.f};

  stage_issue(0);
  stage_write(0);
  __syncthreads();

  for (int c = 0; c < NCHK; c++) {
    if (c+1 < NCHK) stage_issue(c+1);   // loads land during compute below
    int buf = c & 1;
    int kc  = c*CHK;
    // ---- S tile [16q x 32k]: Qhi*Khi + Qlo*Khi + Qhi*Klo, 2 chains for ILP ----
    f32x4 sacc[2];
    #pragma unroll
    for (int kt = 0; kt < 2; kt++) {
      f32x4 a0 = (f32x4){0.f, 0.f, 0.f, 0.f};
      f32x4 a1 = (f32x4){0.f, 0.f, 0.f, 0.f};
      #pragma unroll
      for (int dc = 0; dc < 8; dc += 2) {
        bf16x8 kh0 = *reinterpret_cast<const bf16x8*>(
            &KhiL[buf][(kt*16 + l15)*KLD + dc*32 + quad*8]);
        bf16x8 kl0 = *reinterpret_cast<const bf16x8*>(
            &KloL[buf][(kt*16 + l15)*KLD + dc*32 + quad*8]);
        bf16x8 kh1 = *reinterpret_cast<const bf16x8*>(
            &KhiL[buf][(kt*16 + l15)*KLD + (dc+1)*32 + quad*8]);
        bf16x8 kl1 = *reinterpret_cast<const bf16x8*>(
            &KloL[buf][(kt*16 + l15)*KLD + (dc+1)*32 + quad*8]);
        a0 = __builtin_amdgcn_mfma_f32_16x16x32_bf16(qh[dc], kh0, a0, 0, 0, 0);
        a1 = __builtin_amdgcn_mfma_f32_16x16x32_bf16(qh[dc+1], kh1, a1, 0, 0, 0);
        a0 = __builtin_amdgcn_mfma_f32_16x16x32_bf16(ql[dc], kh0, a0, 0, 0, 0);
        a1 = __builtin_amdgcn_mfma_f32_16x16x32_bf16(ql[dc+1], kh1, a1, 0, 0, 0);
        a0 = __builtin_amdgcn_mfma_f32_16x16x32_bf16(qh[dc], kl0, a0, 0, 0, 0);
        a1 = __builtin_amdgcn_mfma_f32_16x16x32_bf16(qh[dc+1], kl1, a1, 0, 0, 0);
      }
      sacc[kt] = a0 + a1;
    }
    // ---- online softmax (rows = quad*4+r, cols across l15 lanes) ----
    float p[2][4], alpha[4], se[2][4];
    #pragma unroll
    for (int r = 0; r < 4; r++) {
      se[0][r] = mrow[r] ? sacc[0][r]*0.0625f : -1e9f;
      se[1][r] = mrow[r] ? sacc[1][r]*0.0625f : -1e9f;
      float ml = fmaxf(se[0][r], se[1][r]);
      ml = fmaxf(ml, __shfl_xor(ml, 1));
      ml = fmaxf(ml, __shfl_xor(ml, 2));
      ml = fmaxf(ml, __shfl_xor(ml, 4));
      ml = fmaxf(ml, __shfl_xor(ml, 8));
      float mnew = fmaxf(m_run[r], ml);
      alpha[r] = __expf(m_run[r] - mnew);
      p[0][r] = __expf(se[0][r] - mnew);
      p[1][r] = __expf(se[1][r] - mnew);
      float ls = p[0][r] + p[1][r];
      ls += __shfl_xor(ls, 1);
      ls += __shfl_xor(ls, 2);
      ls += __shfl_xor(ls, 4);
      ls += __shfl_xor(ls, 8);
      l_run[r] = l_run[r]*alpha[r] + ls;
      m_run[r] = mnew;
    }
    #pragma unroll
    for (int ht = 0; ht < 16; ht++) {
      acc_o[ht][0] *= alpha[0];
      acc_o[ht][1] *= alpha[1];
      acc_o[ht][2] *= alpha[2];
      acc_o[ht][3] *= alpha[3];
    }
    // ---- RAW fp32 scores to attn (exp deferred to tail); bf16 p' to Ps ----
    #pragma unroll
    for (int kt = 0; kt < 2; kt++) {
      #pragma unroll
      for (int r = 0; r < 4; r++) {
        attn[((size_t)b*S_ + qw + quad*4 + r)*S_ + kc + kt*16 + l15] = se[kt][r];
        Ps[wave][(quad*4 + r)*PSLD + kt*16 + l15] = f2bf(p[kt][r]);
      }
    }
    // ---- AV: P (A-layout via LDS) x V (B-layout, global, L2-hot) ----
    bf16x8 pa = *reinterpret_cast<const bf16x8*>(&Ps[wave][l15*PSLD + quad*8]);
    #pragma unroll
    for (int ht = 0; ht < 16; ht++) {
      const unsigned short* vp = VtB + (size_t)(ht*16 + l15)*S_ + kc + quad*8;
      bf16x8 v = *reinterpret_cast<const bf16x8*>(vp);
      acc_o[ht] = __builtin_amdgcn_mfma_f32_16x16x32_bf16(pa, v, acc_o[ht], 0, 0, 0);
    }
    // ---- hand staged regs to the other buffer; one barrier per chunk ----
    if (c+1 < NCHK) stage_write((c+1) & 1);
    __syncthreads();
  }

  // ---- tail: epilogue + elementwise exp-fixup of this wave's attn rows ----
  float il[4];
  #pragma unroll
  for (int r = 0; r < 4; r++) il[r] = 1.f / l_run[r];
  if (l15 == 0) {
    #pragma unroll
    for (int r = 0; r < 4; r++) {
      Mfin[wave][quad*4 + r] = m_run[r];
      Ilin[wave][quad*4 + r] = il[r];
    }
  }
  #pragma unroll
  for (int ht = 0; ht < 16; ht++) {
    #pragma unroll
    for (int r = 0; r < 4; r++)
      outp[((size_t)b*S_ + qw + quad*4 + r)*H_ + ht*16 + l15] = acc_o[ht][r] * il[r];
  }
  // wave-private LDS: same-wave lgkmcnt ordering suffices
  for (int row = 0; row < 16; row++) {
    float fm = Mfin[wave][row];
    float fi = Ilin[wave][row];
    float* rp = attn + ((size_t)b*S_ + qw + row)*S_;
    #pragma unroll
    for (int g = 0; g < 4; g++) {
      float4* pa4 = reinterpret_cast<float4*>(rp + g*512 + lane*8);
      float4 x0 = pa4[0], x1 = pa4[1];
      x0.x = __expf(x0.x - fm)*fi; x0.y = __expf(x0.y - fm)*fi;
      x0.z = __expf(x0.z - fm)*fi; x0.w = __expf(x0.w - fm)*fi;
      x1.x = __expf(x1.x - fm)*fi; x1.y = __expf(x1.y - fm)*fi;
      x1.z = __expf(x1.z - fm)*fi; x1.w = __expf(x1.w - fm)*fi;
      pa4[0] = x0; pa4[1] = x1;
    }
  }
}

// ---------------------------------------------------------------------------
extern "C" void kernel_launch(void* const* d_in, const int* in_sizes, int n_in,
                              void* d_out, int out_size, void* d_ws, size_t ws_size,
                              hipStream_t stream) {
  const float* enc = (const float*)d_in[0];
  // d_in[1] = decoder_hidden_state: unused by the reference
  const float* z   = (const float*)d_in[2];
  const int* mask  = (const int*)d_in[3];
  const float* Wq  = (const float*)d_in[4];
  const float* Wk  = (const float*)d_in[5];
  const float* Wv  = (const float*)d_in[6];

  char* ws = (char*)d_ws;
  const size_t MB = 1024*1024;
  unsigned short* Qhi = (unsigned short*)(ws);
  unsigned short* Qlo = (unsigned short*)(ws +  8*MB);
  unsigned short* Khi = (unsigned short*)(ws + 16*MB);
  unsigned short* Klo = (unsigned short*)(ws + 24*MB);
  unsigned short* Vt  = (unsigned short*)(ws + 32*MB);
  float* q0 = (float*)(ws + 40*MB);
  float* k0 = q0 + B_*H_;
  float* v0 = k0 + B_*H_;

  float* outp = (float*)d_out;                           // fp32 outputs
  float* attn = outp + (size_t)B_*S_*H_;

  k0_base<<<B_, 256, 0, stream>>>(enc, Wq, Wk, Wv, q0, k0, v0);
  k1_prep<<<B_*(S_/16), 256, 0, stream>>>(z, Wq, Wk, Wv, q0, k0, v0,
                                          Qhi, Qlo, Khi, Klo, Vt);
  k2_flash<<<B_*(S_/64), 256, 0, stream>>>(Qhi, Qlo, Khi, Klo, Vt, mask,
                                           attn, outp);
}

// Round 8
// 514.365 us; speedup vs baseline: 1.5054x; 1.5054x over previous
//
#include <hip/hip_runtime.h>
#include <hip/hip_bf16.h>

#define B_ 8
#define S_ 2048
#define H_ 256
#define Z_ 64
#define CHK 32            // k per staged chunk
#define NQCH 16           // chunks per k-quarter (512/32)
#define KLD 264           // K LDS row stride (shorts) = 528 B
#define VLD 40            // V/Ps row stride (shorts) = 80 B
#define PSLD 40
#define BS (B_*S_)        // 16384 rows

typedef short bf16x8 __attribute__((ext_vector_type(8)));
typedef float f32x4 __attribute__((ext_vector_type(4)));

__device__ __forceinline__ unsigned short f2bf(float f) {
  __hip_bfloat16 h = __float2bfloat16(f);
  return *reinterpret_cast<unsigned short*>(&h);
}
__device__ __forceinline__ float bf2f(unsigned short u) {
  __hip_bfloat16 h;
  *reinterpret_cast<unsigned short*>(&h) = u;
  return __bfloat162float(h);
}

// ---------------------------------------------------------------------------
// k0: per-batch encoder-part projections
__global__ __launch_bounds__(256) void k0_base(
    const float* __restrict__ enc, const float* __restrict__ Wq,
    const float* __restrict__ Wk, const float* __restrict__ Wv,
    float* __restrict__ q0, float* __restrict__ k0, float* __restrict__ v0) {
  int b = blockIdx.x;
  int h = threadIdx.x;
  __shared__ float encs[H_];
  encs[h] = enc[b*H_ + h] + enc[B_*H_ + b*H_ + h];
  __syncthreads();
  float aq = 0.f, ak = 0.f, av = 0.f;
  #pragma unroll 4
  for (int d = 0; d < H_; d++) {
    float e = encs[d];
    aq = fmaf(e, Wq[d*H_ + h], aq);
    ak = fmaf(e, Wk[d*H_ + h], ak);
    av = fmaf(e, Wv[d*H_ + h], av);
  }
  q0[b*H_ + h] = aq;
  k0[b*H_ + h] = ak;
  v0[b*H_ + h] = av;
}

// ---------------------------------------------------------------------------
// k1: z-part projection + hi/lo bf16 split for Q,K; V -> bf16 transposed Vt
__global__ __launch_bounds__(256) void k1_prep(
    const float* __restrict__ z, const float* __restrict__ Wq,
    const float* __restrict__ Wk, const float* __restrict__ Wv,
    const float* __restrict__ q0, const float* __restrict__ k0b, const float* __restrict__ v0,
    unsigned short* __restrict__ Qhi, unsigned short* __restrict__ Qlo,
    unsigned short* __restrict__ Khi, unsigned short* __restrict__ Klo,
    unsigned short* __restrict__ Vt) {
  int b  = blockIdx.x >> 7;
  int st = blockIdx.x & 127;
  int tid = threadIdx.x;      // tid = h
  __shared__ float zs[16*Z_];
  __shared__ float vbuf[16][H_];
  {
    const float4* zp = reinterpret_cast<const float4*>(z + ((size_t)b*S_ + st*16)*Z_);
    reinterpret_cast<float4*>(zs)[tid] = zp[tid];
  }
  __syncthreads();
  float bq = q0[b*H_ + tid], bk = k0b[b*H_ + tid], bv = v0[b*H_ + tid];
  float accq[16], acck[16], accv[16];
  #pragma unroll
  for (int s = 0; s < 16; s++) { accq[s] = bq; acck[s] = bk; accv[s] = bv; }
  #pragma unroll 2
  for (int z0 = 0; z0 < Z_; z0 += 8) {
    float wq[8], wk[8], wv[8];
    #pragma unroll
    for (int j = 0; j < 8; j++) {
      wq[j] = Wq[(H_+z0+j)*H_ + tid];
      wk[j] = Wk[(H_+z0+j)*H_ + tid];
      wv[j] = Wv[(H_+z0+j)*H_ + tid];
    }
    #pragma unroll
    for (int j = 0; j < 8; j++) {
      #pragma unroll
      for (int s = 0; s < 16; s++) {
        float zz = zs[s*Z_ + z0 + j];
        accq[s] = fmaf(zz, wq[j], accq[s]);
        acck[s] = fmaf(zz, wk[j], acck[s]);
        accv[s] = fmaf(zz, wv[j], accv[s]);
      }
    }
  }
  #pragma unroll
  for (int s = 0; s < 16; s++) {
    size_t row = ((size_t)b*S_ + st*16 + s)*H_ + tid;
    unsigned short qh = f2bf(accq[s]);
    Qhi[row] = qh;
    Qlo[row] = f2bf(accq[s] - bf2f(qh));
    unsigned short kh = f2bf(acck[s]);
    Khi[row] = kh;
    Klo[row] = f2bf(acck[s] - bf2f(kh));
    vbuf[s][tid] = accv[s];
  }
  __syncthreads();
  unsigned int pk[8];
  #pragma unroll
  for (int j = 0; j < 8; j++) {
    pk[j] = (unsigned int)f2bf(vbuf[2*j][tid]) |
            ((unsigned int)f2bf(vbuf[2*j+1][tid]) << 16);
  }
  uint4* vt4 = reinterpret_cast<uint4*>(Vt + ((size_t)b*H_ + tid)*S_ + st*16);
  vt4[0] = make_uint4(pk[0], pk[1], pk[2], pk[3]);
  vt4[1] = make_uint4(pk[4], pk[5], pk[6], pk[7]);
}

// ---------------------------------------------------------------------------
// k2: flash attention, k-quarter split ACROSS blocks for TLP (grid 1024 =
// 2 blocks/CU). Block = (64 q rows, 512-k quarter); wave w owns rows
// w*16..w*16+15. K and V staged in single-buffer LDS via register relay
// (2 barriers/chunk). attn gets RAW fp32 scores; partial (m,l,O) to ws;
// k3_combine merges quarters and applies the exp fixup.
__global__ __launch_bounds__(256, 2) void k2_flash(
    const unsigned short* __restrict__ Qhi, const unsigned short* __restrict__ Qlo,
    const unsigned short* __restrict__ Khi, const unsigned short* __restrict__ Klo,
    const unsigned short* __restrict__ Vt, const int* __restrict__ mask,
    float* __restrict__ attn, float* __restrict__ Mq, float* __restrict__ Lq,
    unsigned short* __restrict__ Opart) {
  int bb    = blockIdx.x;
  int b     = bb & 7;           // batch = XCD (L2 locality)
  int strip = (bb >> 3) & 31;
  int kq    = bb >> 8;          // k-quarter 0..3
  int qb    = strip*64;
  int k0q   = kq*512;
  int tid  = threadIdx.x;
  int wave = tid >> 6;
  int lane = tid & 63;
  int l15  = lane & 15;
  int quad = lane >> 4;
  int qw   = qb + wave*16;

  __shared__ __align__(16) unsigned short KhiL[32*KLD];   // 16.5 KB
  __shared__ __align__(16) unsigned short KloL[32*KLD];   // 16.5 KB
  __shared__ __align__(16) unsigned short VtL[256*VLD];   // 20.0 KB
  __shared__ __align__(16) unsigned short Ps[4][16*PSLD]; //  5.0 KB
  // ~58 KB -> 2 blocks/CU at grid 1024 => 2 waves/SIMD

  const unsigned short* KhiB = Khi + (size_t)b*S_*H_;
  const unsigned short* KloB = Klo + (size_t)b*S_*H_;
  const unsigned short* VtB  = Vt  + (size_t)b*H_*S_;

  uint4 rkh[4], rkl[4], rv[4];   // relay registers

  auto stage_issue = [&](int c) {
    int kc = k0q + c*CHK;
    const uint4* ph = reinterpret_cast<const uint4*>(KhiB + (size_t)kc*H_);
    const uint4* pl = reinterpret_cast<const uint4*>(KloB + (size_t)kc*H_);
    #pragma unroll
    for (int i = 0; i < 4; i++) {
      rkh[i] = ph[i*256 + tid];
      rkl[i] = pl[i*256 + tid];
    }
    #pragma unroll
    for (int j = 0; j < 4; j++) {
      int h = j*64 + (tid>>2);
      rv[j] = *reinterpret_cast<const uint4*>(VtB + (size_t)h*S_ + kc + (tid&3)*8);
    }
  };
  auto stage_write = [&]() {
    #pragma unroll
    for (int i = 0; i < 4; i++) {
      int idx = i*256 + tid;
      int row = idx >> 5, col = idx & 31;
      *reinterpret_cast<uint4*>(&KhiL[row*KLD + col*8]) = rkh[i];
      *reinterpret_cast<uint4*>(&KloL[row*KLD + col*8]) = rkl[i];
    }
    #pragma unroll
    for (int j = 0; j < 4; j++) {
      int h = j*64 + (tid>>2);
      *reinterpret_cast<uint4*>(&VtL[h*VLD + (tid&3)*8]) = rv[j];
    }
  };

  // Q fragments: A[m=l15][k=quad*8+j]
  bf16x8 qh[8], ql[8];
  {
    const unsigned short* qhp = Qhi + ((size_t)b*S_ + qw + l15)*H_ + quad*8;
    const unsigned short* qlp = Qlo + ((size_t)b*S_ + qw + l15)*H_ + quad*8;
    #pragma unroll
    for (int dc = 0; dc < 8; dc++) {
      qh[dc] = *reinterpret_cast<const bf16x8*>(qhp + dc*32);
      ql[dc] = *reinterpret_cast<const bf16x8*>(qlp + dc*32);
    }
  }
  int mrow[4];
  #pragma unroll
  for (int r = 0; r < 4; r++) mrow[r] = mask[b*S_ + qw + quad*4 + r];

  f32x4 acc_o[16];
  #pragma unroll
  for (int ht = 0; ht < 16; ht++) acc_o[ht] = (f32x4){0.f, 0.f, 0.f, 0.f};
  float m_run[4] = {-1e30f, -1e30f, -1e30f, -1e30f};
  float l_run[4] = {0.f, 0.f, 0.f, 0.f};

  stage_issue(0);
  stage_write();
  __syncthreads();

  for (int c = 0; c < NQCH; c++) {
    if (c+1 < NQCH) stage_issue(c+1);   // into registers; lands during compute
    int kc = k0q + c*CHK;
    // ---- S tile [16q x 32k]: Qhi*Khi + Qlo*Khi + Qhi*Klo, 2 chains ----
    f32x4 sacc[2];
    #pragma unroll
    for (int kt = 0; kt < 2; kt++) {
      f32x4 a0 = (f32x4){0.f, 0.f, 0.f, 0.f};
      f32x4 a1 = (f32x4){0.f, 0.f, 0.f, 0.f};
      #pragma unroll
      for (int dc = 0; dc < 8; dc += 2) {
        bf16x8 kh0 = *reinterpret_cast<const bf16x8*>(
            &KhiL[(kt*16 + l15)*KLD + dc*32 + quad*8]);
        bf16x8 kl0 = *reinterpret_cast<const bf16x8*>(
            &KloL[(kt*16 + l15)*KLD + dc*32 + quad*8]);
        bf16x8 kh1 = *reinterpret_cast<const bf16x8*>(
            &KhiL[(kt*16 + l15)*KLD + (dc+1)*32 + quad*8]);
        bf16x8 kl1 = *reinterpret_cast<const bf16x8*>(
            &KloL[(kt*16 + l15)*KLD + (dc+1)*32 + quad*8]);
        a0 = __builtin_amdgcn_mfma_f32_16x16x32_bf16(qh[dc], kh0, a0, 0, 0, 0);
        a1 = __builtin_amdgcn_mfma_f32_16x16x32_bf16(qh[dc+1], kh1, a1, 0, 0, 0);
        a0 = __builtin_amdgcn_mfma_f32_16x16x32_bf16(ql[dc], kh0, a0, 0, 0, 0);
        a1 = __builtin_amdgcn_mfma_f32_16x16x32_bf16(ql[dc+1], kh1, a1, 0, 0, 0);
        a0 = __builtin_amdgcn_mfma_f32_16x16x32_bf16(qh[dc], kl0, a0, 0, 0, 0);
        a1 = __builtin_amdgcn_mfma_f32_16x16x32_bf16(qh[dc+1], kl1, a1, 0, 0, 0);
      }
      sacc[kt] = a0 + a1;
    }
    // ---- online softmax ----
    float p[2][4], alpha[4], se[2][4];
    #pragma unroll
    for (int r = 0; r < 4; r++) {
      se[0][r] = mrow[r] ? sacc[0][r]*0.0625f : -1e9f;
      se[1][r] = mrow[r] ? sacc[1][r]*0.0625f : -1e9f;
      float ml = fmaxf(se[0][r], se[1][r]);
      ml = fmaxf(ml, __shfl_xor(ml, 1));
      ml = fmaxf(ml, __shfl_xor(ml, 2));
      ml = fmaxf(ml, __shfl_xor(ml, 4));
      ml = fmaxf(ml, __shfl_xor(ml, 8));
      float mnew = fmaxf(m_run[r], ml);
      alpha[r] = __expf(m_run[r] - mnew);
      p[0][r] = __expf(se[0][r] - mnew);
      p[1][r] = __expf(se[1][r] - mnew);
      float ls = p[0][r] + p[1][r];
      ls += __shfl_xor(ls, 1);
      ls += __shfl_xor(ls, 2);
      ls += __shfl_xor(ls, 4);
      ls += __shfl_xor(ls, 8);
      l_run[r] = l_run[r]*alpha[r] + ls;
      m_run[r] = mnew;
    }
    #pragma unroll
    for (int ht = 0; ht < 16; ht++) {
      acc_o[ht][0] *= alpha[0];
      acc_o[ht][1] *= alpha[1];
      acc_o[ht][2] *= alpha[2];
      acc_o[ht][3] *= alpha[3];
    }
    // ---- RAW fp32 scores to attn; bf16 p' to Ps (wave-private) ----
    #pragma unroll
    for (int kt = 0; kt < 2; kt++) {
      #pragma unroll
      for (int r = 0; r < 4; r++) {
        attn[((size_t)b*S_ + qw + quad*4 + r)*S_ + kc + kt*16 + l15] = se[kt][r];
        Ps[wave][(quad*4 + r)*PSLD + kt*16 + l15] = f2bf(p[kt][r]);
      }
    }
    // ---- AV from LDS ----
    bf16x8 pa = *reinterpret_cast<const bf16x8*>(&Ps[wave][l15*PSLD + quad*8]);
    #pragma unroll
    for (int ht = 0; ht < 16; ht++) {
      bf16x8 v = *reinterpret_cast<const bf16x8*>(&VtL[(ht*16 + l15)*VLD + quad*8]);
      acc_o[ht] = __builtin_amdgcn_mfma_f32_16x16x32_bf16(pa, v, acc_o[ht], 0, 0, 0);
    }
    __syncthreads();                     // all readers done with LDS tiles
    if (c+1 < NQCH) {
      stage_write();                     // overwrite single buffer
      __syncthreads();                   // writes visible before next compute
    }
  }

  // ---- tail: partial (m,l) + unnormalized partial O (bf16) to workspace ----
  if (l15 == 0) {
    #pragma unroll
    for (int r = 0; r < 4; r++) {
      int idx = kq*BS + b*S_ + qw + quad*4 + r;
      Mq[idx] = m_run[r];
      Lq[idx] = l_run[r];
    }
  }
  #pragma unroll
  for (int ht = 0; ht < 16; ht++) {
    #pragma unroll
    for (int r = 0; r < 4; r++) {
      size_t idx = ((size_t)kq*BS + b*S_ + qw + quad*4 + r)*H_ + ht*16 + l15;
      Opart[idx] = f2bf(acc_o[ht][r]);
    }
  }
}

// ---------------------------------------------------------------------------
// k3: per row, merge the 4 k-quarter partials and finalize both outputs:
//   m = max m_q; l = sum l_q exp(m_q-m); out = sum e_q O_q / l;
//   attn = exp(se_raw - m) / l   (raw scores are frame-free)
__global__ __launch_bounds__(256) void k3_combine(
    const float* __restrict__ Mq, const float* __restrict__ Lq,
    const unsigned short* __restrict__ Opart,
    float* __restrict__ attn, float* __restrict__ outp) {
  int gr  = blockIdx.x;     // b*S_ + q
  int tid = threadIdx.x;
  float m0 = Mq[gr], m1 = Mq[BS + gr], m2 = Mq[2*BS + gr], m3 = Mq[3*BS + gr];
  float m = fmaxf(fmaxf(m0, m1), fmaxf(m2, m3));
  float e0 = __expf(m0 - m), e1 = __expf(m1 - m);
  float e2 = __expf(m2 - m), e3 = __expf(m3 - m);
  float l = Lq[gr]*e0 + Lq[BS + gr]*e1 + Lq[2*BS + gr]*e2 + Lq[3*BS + gr]*e3;
  float il = 1.f / l;
  // out: one h per thread
  float o = e0*bf2f(Opart[(size_t)gr*H_ + tid])
          + e1*bf2f(Opart[((size_t)BS + gr)*H_ + tid])
          + e2*bf2f(Opart[((size_t)2*BS + gr)*H_ + tid])
          + e3*bf2f(Opart[((size_t)3*BS + gr)*H_ + tid]);
  outp[(size_t)gr*H_ + tid] = o * il;
  // attn: 8 consecutive floats per thread
  float4* pa = reinterpret_cast<float4*>(attn + (size_t)gr*S_ + tid*8);
  float4 x0 = pa[0], x1 = pa[1];
  x0.x = __expf(x0.x - m)*il; x0.y = __expf(x0.y - m)*il;
  x0.z = __expf(x0.z - m)*il; x0.w = __expf(x0.w - m)*il;
  x1.x = __expf(x1.x - m)*il; x1.y = __expf(x1.y - m)*il;
  x1.z = __expf(x1.z - m)*il; x1.w = __expf(x1.w - m)*il;
  pa[0] = x0; pa[1] = x1;
}

// ---------------------------------------------------------------------------
extern "C" void kernel_launch(void* const* d_in, const int* in_sizes, int n_in,
                              void* d_out, int out_size, void* d_ws, size_t ws_size,
                              hipStream_t stream) {
  const float* enc = (const float*)d_in[0];
  // d_in[1] = decoder_hidden_state: unused by the reference
  const float* z   = (const float*)d_in[2];
  const int* mask  = (const int*)d_in[3];
  const float* Wq  = (const float*)d_in[4];
  const float* Wk  = (const float*)d_in[5];
  const float* Wv  = (const float*)d_in[6];

  char* ws = (char*)d_ws;
  const size_t MB = 1024*1024;
  unsigned short* Qhi = (unsigned short*)(ws);
  unsigned short* Qlo = (unsigned short*)(ws +  8*MB);
  unsigned short* Khi = (unsigned short*)(ws + 16*MB);
  unsigned short* Klo = (unsigned short*)(ws + 24*MB);
  unsigned short* Vt  = (unsigned short*)(ws + 32*MB);
  float* q0 = (float*)(ws + 40*MB);
  float* k0 = q0 + B_*H_;
  float* v0 = k0 + B_*H_;
  float* Mq = (float*)(ws + 41*MB);                 // [4][B*S]
  float* Lq = (float*)(ws + 41*MB + 512*1024);      // [4][B*S]
  unsigned short* Opart = (unsigned short*)(ws + 42*MB);  // [4][B*S][H] bf16 = 32 MB

  float* outp = (float*)d_out;
  float* attn = outp + (size_t)B_*S_*H_;

  k0_base<<<B_, 256, 0, stream>>>(enc, Wq, Wk, Wv, q0, k0, v0);
  k1_prep<<<B_*(S_/16), 256, 0, stream>>>(z, Wq, Wk, Wv, q0, k0, v0,
                                          Qhi, Qlo, Khi, Klo, Vt);
  k2_flash<<<B_*(S_/64)*4, 256, 0, stream>>>(Qhi, Qlo, Khi, Klo, Vt, mask,
                                             attn, Mq, Lq, Opart);
  k3_combine<<<B_*S_, 256, 0, stream>>>(Mq, Lq, Opart, attn, outp);
}

// Round 9
// 365.949 us; speedup vs baseline: 2.1159x; 1.4056x over previous
//
#include <hip/hip_runtime.h>
#include <hip/hip_bf16.h>

#define B_ 8
#define S_ 2048
#define H_ 256
#define Z_ 64
#define CHK 32            // k per staged chunk
#define NQCH 16           // chunks per 512-k quarter
#define BS (B_*S_)        // 16384 rows

typedef short bf16x8 __attribute__((ext_vector_type(8)));
typedef float f32x4 __attribute__((ext_vector_type(4)));

__device__ __forceinline__ unsigned short f2bf(float f) {
  __hip_bfloat16 h = __float2bfloat16(f);
  return *reinterpret_cast<unsigned short*>(&h);
}
__device__ __forceinline__ float bf2f(unsigned short u) {
  __hip_bfloat16 h;
  *reinterpret_cast<unsigned short*>(&h) = u;
  return __bfloat162float(h);
}

// async global->LDS DMA, 16 B/lane: LDS dest = wave-uniform base + lane*16,
// global src = per-lane address. Completion is forced by the vmcnt drain at
// the next __syncthreads.
__device__ __forceinline__ void gl_lds16(const void* g, void* l) {
  __builtin_amdgcn_global_load_lds(
      (const __attribute__((address_space(1))) unsigned int*)(uintptr_t)g,
      (__attribute__((address_space(3))) unsigned int*)(uintptr_t)l,
      16, 0, 0);
}

// ---------------------------------------------------------------------------
// k0: per-batch encoder-part projections
__global__ __launch_bounds__(256) void k0_base(
    const float* __restrict__ enc, const float* __restrict__ Wq,
    const float* __restrict__ Wk, const float* __restrict__ Wv,
    float* __restrict__ q0, float* __restrict__ k0, float* __restrict__ v0) {
  int b = blockIdx.x;
  int h = threadIdx.x;
  __shared__ float encs[H_];
  encs[h] = enc[b*H_ + h] + enc[B_*H_ + b*H_ + h];
  __syncthreads();
  float aq = 0.f, ak = 0.f, av = 0.f;
  #pragma unroll 4
  for (int d = 0; d < H_; d++) {
    float e = encs[d];
    aq = fmaf(e, Wq[d*H_ + h], aq);
    ak = fmaf(e, Wk[d*H_ + h], ak);
    av = fmaf(e, Wv[d*H_ + h], av);
  }
  q0[b*H_ + h] = aq;
  k0[b*H_ + h] = ak;
  v0[b*H_ + h] = av;
}

// ---------------------------------------------------------------------------
// k1: z-part projection + hi/lo bf16 split for Q,K; V -> bf16 transposed Vt
__global__ __launch_bounds__(256) void k1_prep(
    const float* __restrict__ z, const float* __restrict__ Wq,
    const float* __restrict__ Wk, const float* __restrict__ Wv,
    const float* __restrict__ q0, const float* __restrict__ k0b, const float* __restrict__ v0,
    unsigned short* __restrict__ Qhi, unsigned short* __restrict__ Qlo,
    unsigned short* __restrict__ Khi, unsigned short* __restrict__ Klo,
    unsigned short* __restrict__ Vt) {
  int b  = blockIdx.x >> 7;
  int st = blockIdx.x & 127;
  int tid = threadIdx.x;      // tid = h
  __shared__ float zs[16*Z_];
  __shared__ float vbuf[16][H_];
  {
    const float4* zp = reinterpret_cast<const float4*>(z + ((size_t)b*S_ + st*16)*Z_);
    reinterpret_cast<float4*>(zs)[tid] = zp[tid];
  }
  __syncthreads();
  float bq = q0[b*H_ + tid], bk = k0b[b*H_ + tid], bv = v0[b*H_ + tid];
  float accq[16], acck[16], accv[16];
  #pragma unroll
  for (int s = 0; s < 16; s++) { accq[s] = bq; acck[s] = bk; accv[s] = bv; }
  #pragma unroll 2
  for (int z0 = 0; z0 < Z_; z0 += 8) {
    float wq[8], wk[8], wv[8];
    #pragma unroll
    for (int j = 0; j < 8; j++) {
      wq[j] = Wq[(H_+z0+j)*H_ + tid];
      wk[j] = Wk[(H_+z0+j)*H_ + tid];
      wv[j] = Wv[(H_+z0+j)*H_ + tid];
    }
    #pragma unroll
    for (int j = 0; j < 8; j++) {
      #pragma unroll
      for (int s = 0; s < 16; s++) {
        float zz = zs[s*Z_ + z0 + j];
        accq[s] = fmaf(zz, wq[j], accq[s]);
        acck[s] = fmaf(zz, wk[j], acck[s]);
        accv[s] = fmaf(zz, wv[j], accv[s]);
      }
    }
  }
  #pragma unroll
  for (int s = 0; s < 16; s++) {
    size_t row = ((size_t)b*S_ + st*16 + s)*H_ + tid;
    unsigned short qh = f2bf(accq[s]);
    Qhi[row] = qh;
    Qlo[row] = f2bf(accq[s] - bf2f(qh));
    unsigned short kh = f2bf(acck[s]);
    Khi[row] = kh;
    Klo[row] = f2bf(acck[s] - bf2f(kh));
    vbuf[s][tid] = accv[s];
  }
  __syncthreads();
  unsigned int pk[8];
  #pragma unroll
  for (int j = 0; j < 8; j++) {
    pk[j] = (unsigned int)f2bf(vbuf[2*j][tid]) |
            ((unsigned int)f2bf(vbuf[2*j+1][tid]) << 16);
  }
  uint4* vt4 = reinterpret_cast<uint4*>(Vt + ((size_t)b*H_ + tid)*S_ + st*16);
  vt4[0] = make_uint4(pk[0], pk[1], pk[2], pk[3]);
  vt4[1] = make_uint4(pk[4], pk[5], pk[6], pk[7]);
}

// ---------------------------------------------------------------------------
// k2: flash attention, k-quarter split across blocks. K/V staged via async
// global_load_lds DMA (no relay registers -> no spills). K stored XOR-swizzled
// (slot c holds chunk c^row) so unpadded rows stay conflict-free for the MFMA
// fragment reads. Single LDS buffer, 2 barriers/chunk (barrier vmcnt drain =
// DMA completion wait). Partial (m,l,O) per quarter to ws; k3 combines.
__global__ __launch_bounds__(256, 2) void k2_flash(
    const unsigned short* __restrict__ Qhi, const unsigned short* __restrict__ Qlo,
    const unsigned short* __restrict__ Khi, const unsigned short* __restrict__ Klo,
    const unsigned short* __restrict__ Vt, const int* __restrict__ mask,
    float* __restrict__ attn, float* __restrict__ Mq, float* __restrict__ Lq,
    unsigned short* __restrict__ Opart) {
  int bb    = blockIdx.x;
  int b     = bb & 7;           // batch = XCD (L2 locality)
  int strip = (bb >> 3) & 31;
  int kq    = bb >> 8;          // k-quarter 0..3
  int qb    = strip*64;
  int k0q   = kq*512;
  int tid  = threadIdx.x;
  int wave = tid >> 6;
  int lane = tid & 63;
  int l15  = lane & 15;
  int quad = lane >> 4;
  int qw   = qb + wave*16;

  __shared__ __align__(16) unsigned short KhiL[32*256];   // 16 KB, XOR-swizzled
  __shared__ __align__(16) unsigned short KloL[32*256];   // 16 KB, XOR-swizzled
  __shared__ __align__(16) unsigned short VtL[256*32];    // 16 KB, natural
  __shared__ __align__(16) unsigned short Ps[4][16*32];   //  4 KB
  // 52 KB total

  const unsigned short* KhiB = Khi + (size_t)b*S_*H_;
  const unsigned short* KloB = Klo + (size_t)b*S_*H_;
  const unsigned short* VtB  = Vt  + (size_t)b*H_*S_;

  int sub = lane >> 5;          // K-DMA: which of 2 rows in the 1KB instr
  int c5  = lane & 31;          // K-DMA: 16B chunk within row
  int hl  = lane >> 2;          // V-DMA: h-row within 16
  int jj  = lane & 3;           // V-DMA: 16B chunk within 64B row

  auto dma_chunk = [&](int c) {
    int kc = k0q + c*CHK;
    #pragma unroll
    for (int t = 0; t < 4; t++) {
      int i = wave*4 + t;                 // 16 x 1KB instrs split over 4 waves
      int row = i*2 + sub;                // K row 0..31
      size_t gs = (size_t)(kc + row)*H_ + ((c5 ^ row)*8);  // shorts, swizzled
      gl_lds16(KhiB + gs, &KhiL[i*512]);
      gl_lds16(KloB + gs, &KloL[i*512]);
    }
    #pragma unroll
    for (int t = 0; t < 4; t++) {
      int i = wave*4 + t;
      int h = i*16 + hl;
      gl_lds16(VtB + (size_t)h*S_ + kc + jj*8, &VtL[i*512]);
    }
  };

  // Q fragments: A[m=l15][k=quad*8+j]
  bf16x8 qh[8], ql[8];
  {
    const unsigned short* qhp = Qhi + ((size_t)b*S_ + qw + l15)*H_ + quad*8;
    const unsigned short* qlp = Qlo + ((size_t)b*S_ + qw + l15)*H_ + quad*8;
    #pragma unroll
    for (int dc = 0; dc < 8; dc++) {
      qh[dc] = *reinterpret_cast<const bf16x8*>(qhp + dc*32);
      ql[dc] = *reinterpret_cast<const bf16x8*>(qlp + dc*32);
    }
  }
  int mrow[4];
  #pragma unroll
  for (int r = 0; r < 4; r++) mrow[r] = mask[b*S_ + qw + quad*4 + r];

  f32x4 acc_o[16];
  #pragma unroll
  for (int ht = 0; ht < 16; ht++) acc_o[ht] = (f32x4){0.f, 0.f, 0.f, 0.f};
  float m_run[4] = {-1e30f, -1e30f, -1e30f, -1e30f};
  float l_run[4] = {0.f, 0.f, 0.f, 0.f};

  dma_chunk(0);
  __syncthreads();     // vmcnt drain -> chunk 0 resident

  for (int c = 0; c < NQCH; c++) {
    int kc = k0q + c*CHK;
    // ---- S tile [16q x 32k]: Qhi*Khi + Qlo*Khi + Qhi*Klo, 2 chains ----
    f32x4 sacc[2];
    #pragma unroll
    for (int kt = 0; kt < 2; kt++) {
      int row = kt*16 + l15;
      const unsigned short* khb = &KhiL[row*256];
      const unsigned short* klb = &KloL[row*256];
      f32x4 a0 = (f32x4){0.f, 0.f, 0.f, 0.f};
      f32x4 a1 = (f32x4){0.f, 0.f, 0.f, 0.f};
      #pragma unroll
      for (int dc = 0; dc < 8; dc += 2) {
        int s0 = ((dc*4 + quad) ^ row) * 8;       // XOR-swizzled slot
        int s1 = (((dc+1)*4 + quad) ^ row) * 8;
        bf16x8 kh0 = *reinterpret_cast<const bf16x8*>(khb + s0);
        bf16x8 kl0 = *reinterpret_cast<const bf16x8*>(klb + s0);
        bf16x8 kh1 = *reinterpret_cast<const bf16x8*>(khb + s1);
        bf16x8 kl1 = *reinterpret_cast<const bf16x8*>(klb + s1);
        a0 = __builtin_amdgcn_mfma_f32_16x16x32_bf16(qh[dc], kh0, a0, 0, 0, 0);
        a1 = __builtin_amdgcn_mfma_f32_16x16x32_bf16(qh[dc+1], kh1, a1, 0, 0, 0);
        a0 = __builtin_amdgcn_mfma_f32_16x16x32_bf16(ql[dc], kh0, a0, 0, 0, 0);
        a1 = __builtin_amdgcn_mfma_f32_16x16x32_bf16(ql[dc+1], kh1, a1, 0, 0, 0);
        a0 = __builtin_amdgcn_mfma_f32_16x16x32_bf16(qh[dc], kl0, a0, 0, 0, 0);
        a1 = __builtin_amdgcn_mfma_f32_16x16x32_bf16(qh[dc+1], kl1, a1, 0, 0, 0);
      }
      sacc[kt] = a0 + a1;
    }
    // ---- online softmax ----
    float p[2][4], alpha[4], se[2][4];
    #pragma unroll
    for (int r = 0; r < 4; r++) {
      se[0][r] = mrow[r] ? sacc[0][r]*0.0625f : -1e9f;
      se[1][r] = mrow[r] ? sacc[1][r]*0.0625f : -1e9f;
      float ml = fmaxf(se[0][r], se[1][r]);
      ml = fmaxf(ml, __shfl_xor(ml, 1));
      ml = fmaxf(ml, __shfl_xor(ml, 2));
      ml = fmaxf(ml, __shfl_xor(ml, 4));
      ml = fmaxf(ml, __shfl_xor(ml, 8));
      float mnew = fmaxf(m_run[r], ml);
      alpha[r] = __expf(m_run[r] - mnew);
      p[0][r] = __expf(se[0][r] - mnew);
      p[1][r] = __expf(se[1][r] - mnew);
      float ls = p[0][r] + p[1][r];
      ls += __shfl_xor(ls, 1);
      ls += __shfl_xor(ls, 2);
      ls += __shfl_xor(ls, 4);
      ls += __shfl_xor(ls, 8);
      l_run[r] = l_run[r]*alpha[r] + ls;
      m_run[r] = mnew;
    }
    #pragma unroll
    for (int ht = 0; ht < 16; ht++) {
      acc_o[ht][0] *= alpha[0];
      acc_o[ht][1] *= alpha[1];
      acc_o[ht][2] *= alpha[2];
      acc_o[ht][3] *= alpha[3];
    }
    // ---- RAW fp32 scores to attn; bf16 p' to Ps (wave-private) ----
    #pragma unroll
    for (int kt = 0; kt < 2; kt++) {
      #pragma unroll
      for (int r = 0; r < 4; r++) {
        attn[((size_t)b*S_ + qw + quad*4 + r)*S_ + kc + kt*16 + l15] = se[kt][r];
        Ps[wave][(quad*4 + r)*32 + kt*16 + l15] = f2bf(p[kt][r]);
      }
    }
    // ---- AV from LDS ----
    bf16x8 pa = *reinterpret_cast<const bf16x8*>(&Ps[wave][l15*32 + quad*8]);
    #pragma unroll
    for (int ht = 0; ht < 16; ht++) {
      bf16x8 v = *reinterpret_cast<const bf16x8*>(&VtL[(ht*16 + l15)*32 + quad*8]);
      acc_o[ht] = __builtin_amdgcn_mfma_f32_16x16x32_bf16(pa, v, acc_o[ht], 0, 0, 0);
    }
    __syncthreads();                     // readers done with this chunk
    if (c+1 < NQCH) {
      dma_chunk(c+1);                    // async DMA into the single buffer
      __syncthreads();                   // vmcnt drain -> chunk resident
    }
  }

  // ---- tail: partial (m,l) + unnormalized partial O (bf16) to workspace ----
  if (l15 == 0) {
    #pragma unroll
    for (int r = 0; r < 4; r++) {
      int idx = kq*BS + b*S_ + qw + quad*4 + r;
      Mq[idx] = m_run[r];
      Lq[idx] = l_run[r];
    }
  }
  #pragma unroll
  for (int ht = 0; ht < 16; ht++) {
    #pragma unroll
    for (int r = 0; r < 4; r++) {
      size_t idx = ((size_t)kq*BS + b*S_ + qw + quad*4 + r)*H_ + ht*16 + l15;
      Opart[idx] = f2bf(acc_o[ht][r]);
    }
  }
}

// ---------------------------------------------------------------------------
// k3: merge the 4 k-quarter partials, finalize out and attn
__global__ __launch_bounds__(256) void k3_combine(
    const float* __restrict__ Mq, const float* __restrict__ Lq,
    const unsigned short* __restrict__ Opart,
    float* __restrict__ attn, float* __restrict__ outp) {
  int gr  = blockIdx.x;     // b*S_ + q
  int tid = threadIdx.x;
  float m0 = Mq[gr], m1 = Mq[BS + gr], m2 = Mq[2*BS + gr], m3 = Mq[3*BS + gr];
  float m = fmaxf(fmaxf(m0, m1), fmaxf(m2, m3));
  float e0 = __expf(m0 - m), e1 = __expf(m1 - m);
  float e2 = __expf(m2 - m), e3 = __expf(m3 - m);
  float l = Lq[gr]*e0 + Lq[BS + gr]*e1 + Lq[2*BS + gr]*e2 + Lq[3*BS + gr]*e3;
  float il = 1.f / l;
  float o = e0*bf2f(Opart[(size_t)gr*H_ + tid])
          + e1*bf2f(Opart[((size_t)BS + gr)*H_ + tid])
          + e2*bf2f(Opart[((size_t)2*BS + gr)*H_ + tid])
          + e3*bf2f(Opart[((size_t)3*BS + gr)*H_ + tid]);
  outp[(size_t)gr*H_ + tid] = o * il;
  float4* pa = reinterpret_cast<float4*>(attn + (size_t)gr*S_ + tid*8);
  float4 x0 = pa[0], x1 = pa[1];
  x0.x = __expf(x0.x - m)*il; x0.y = __expf(x0.y - m)*il;
  x0.z = __expf(x0.z - m)*il; x0.w = __expf(x0.w - m)*il;
  x1.x = __expf(x1.x - m)*il; x1.y = __expf(x1.y - m)*il;
  x1.z = __expf(x1.z - m)*il; x1.w = __expf(x1.w - m)*il;
  pa[0] = x0; pa[1] = x1;
}

// ---------------------------------------------------------------------------
extern "C" void kernel_launch(void* const* d_in, const int* in_sizes, int n_in,
                              void* d_out, int out_size, void* d_ws, size_t ws_size,
                              hipStream_t stream) {
  const float* enc = (const float*)d_in[0];
  // d_in[1] = decoder_hidden_state: unused by the reference
  const float* z   = (const float*)d_in[2];
  const int* mask  = (const int*)d_in[3];
  const float* Wq  = (const float*)d_in[4];
  const float* Wk  = (const float*)d_in[5];
  const float* Wv  = (const float*)d_in[6];

  char* ws = (char*)d_ws;
  const size_t MB = 1024*1024;
  unsigned short* Qhi = (unsigned short*)(ws);
  unsigned short* Qlo = (unsigned short*)(ws +  8*MB);
  unsigned short* Khi = (unsigned short*)(ws + 16*MB);
  unsigned short* Klo = (unsigned short*)(ws + 24*MB);
  unsigned short* Vt  = (unsigned short*)(ws + 32*MB);
  float* q0 = (float*)(ws + 40*MB);
  float* k0 = q0 + B_*H_;
  float* v0 = k0 + B_*H_;
  float* Mq = (float*)(ws + 41*MB);                 // [4][B*S]
  float* Lq = (float*)(ws + 41*MB + 512*1024);      // [4][B*S]
  unsigned short* Opart = (unsigned short*)(ws + 42*MB);  // [4][B*S][H] bf16 = 32 MB

  float* outp = (float*)d_out;
  float* attn = outp + (size_t)B_*S_*H_;

  k0_base<<<B_, 256, 0, stream>>>(enc, Wq, Wk, Wv, q0, k0, v0);
  k1_prep<<<B_*(S_/16), 256, 0, stream>>>(z, Wq, Wk, Wv, q0, k0, v0,
                                          Qhi, Qlo, Khi, Klo, Vt);
  k2_flash<<<B_*(S_/64)*4, 256, 0, stream>>>(Qhi, Qlo, Khi, Klo, Vt, mask,
                                             attn, Mq, Lq, Opart);
  k3_combine<<<B_*S_, 256, 0, stream>>>(Mq, Lq, Opart, attn, outp);
}